// Round 1
// baseline (1458.071 us; speedup 1.0000x reference)
//
#include <hip/hip_runtime.h>

#define NN 150000
#define EE 600000
#define HH 4
#define CC 64
#define GG 4096
#define INF 9

__device__ __forceinline__ float lrelu(float a){ return a > 0.f ? a : 0.2f*a; }

// ---------------- CSR build ----------------
__global__ __launch_bounds__(256) void k_count(const int* __restrict__ dst, int* __restrict__ deg){
  int e = blockIdx.x*256 + threadIdx.x;
  if (e < EE) atomicAdd(&deg[dst[e]], 1);
}

__global__ __launch_bounds__(256) void k_scan1(const int* __restrict__ deg, int* __restrict__ excl, int* __restrict__ bsum){
  __shared__ int s[256];
  int tid = threadIdx.x, gid = blockIdx.x*256 + tid;
  int v = (gid < NN) ? deg[gid] : 0;
  s[tid] = v; __syncthreads();
  for (int off = 1; off < 256; off <<= 1){
    int t = (tid >= off) ? s[tid-off] : 0; __syncthreads();
    s[tid] += t; __syncthreads();
  }
  if (gid < NN) excl[gid] = s[tid] - v;   // block-local exclusive
  if (tid == 255) bsum[blockIdx.x] = s[255];
}

__global__ __launch_bounds__(1024) void k_scan2(int* __restrict__ bsum, int nb){
  __shared__ int s[1024];
  int tid = threadIdx.x;
  int v = (tid < nb) ? bsum[tid] : 0;
  s[tid] = v; __syncthreads();
  for (int off = 1; off < 1024; off <<= 1){
    int t = (tid >= off) ? s[tid-off] : 0; __syncthreads();
    s[tid] += t; __syncthreads();
  }
  if (tid < nb) bsum[tid] = s[tid] - v;   // exclusive block offsets
}

__global__ __launch_bounds__(256) void k_scan3(int* __restrict__ rp, const int* __restrict__ bsum){
  int gid = blockIdx.x*256 + threadIdx.x;
  if (gid < NN) rp[gid] += bsum[blockIdx.x];
  if (gid == 0) rp[NN] = EE;
}

__global__ __launch_bounds__(256) void k_fill(const int* __restrict__ src, const int* __restrict__ dst,
                                              const int* __restrict__ rp, int* __restrict__ fill,
                                              int* __restrict__ col){
  int e = blockIdx.x*256 + threadIdx.x;
  if (e < EE){
    int d = dst[e];
    int pos = rp[d] + atomicAdd(&fill[d], 1);
    col[pos] = src[e];
  }
}

// batch is sorted; gstart[g] = first node of graph g (gstart[GG] = NN)
__global__ __launch_bounds__(256) void k_gstart(const int* __restrict__ batch, int* __restrict__ gstart){
  int g = blockIdx.x*256 + threadIdx.x;
  if (g > GG) return;
  int lo = 0, hi = NN;
  while (lo < hi){ int mid = (lo+hi) >> 1; if (batch[mid] < g) lo = mid+1; else hi = mid; }
  gstart[g] = lo;
}

// ---------------- feature transform: h_feat[N,256] = hin[N,K] @ W[K,256] ----------------
template<int K>
__global__ __launch_bounds__(256) void k_gemm(const float* __restrict__ hin, const float* __restrict__ W,
                                              float* __restrict__ hf){
  int base = blockIdx.x * 16;
  int t = threadIdx.x;
  __shared__ float xs[16][K];
  for (int i = t; i < 16*K; i += 256){
    int node = base + i/K;
    xs[i/K][i%K] = (node < NN) ? hin[(size_t)node*K + i%K] : 0.f;
  }
  __syncthreads();
  float acc[16];
  #pragma unroll
  for (int i = 0; i < 16; i++) acc[i] = 0.f;
  for (int k = 0; k < K; k++){
    float w = W[k*256 + t];
    #pragma unroll
    for (int i = 0; i < 16; i++) acc[i] += xs[i][k] * w;
  }
  #pragma unroll
  for (int i = 0; i < 16; i++){
    int node = base + i;
    if (node < NN) hf[(size_t)node*256 + t] = acc[i];
  }
}

// ---------------- per-node attention logits: es/ed [N,4] ----------------
__global__ __launch_bounds__(256) void k_esed(const float* __restrict__ hf, const float* __restrict__ asrc,
                                              const float* __restrict__ adst, float* __restrict__ es,
                                              float* __restrict__ ed){
  int w = (blockIdx.x*256 + threadIdx.x) >> 6;   // wave per node
  int lane = threadIdx.x & 63;
  if (w >= NN) return;
  const float* hr = hf + (size_t)w*256;
  float ps[HH], pd[HH];
  #pragma unroll
  for (int h = 0; h < HH; h++){
    float v = hr[h*64 + lane];
    ps[h] = v * asrc[h*64 + lane];
    pd[h] = v * adst[h*64 + lane];
  }
  #pragma unroll
  for (int off = 32; off; off >>= 1){
    #pragma unroll
    for (int h = 0; h < HH; h++){
      ps[h] += __shfl_down(ps[h], off);
      pd[h] += __shfl_down(pd[h], off);
    }
  }
  if (lane == 0){
    #pragma unroll
    for (int h = 0; h < HH; h++){ es[(size_t)w*4 + h] = ps[h]; ed[(size_t)w*4 + h] = pd[h]; }
  }
}

// ---------------- attention + aggregation + epilogue (one wave per node) ----------------
__global__ __launch_bounds__(256) void k_aggr(const float* __restrict__ hf, const float* __restrict__ es4,
     const float* __restrict__ ed4, const int* __restrict__ rp, const int* __restrict__ col,
     const float* __restrict__ bias, const float* __restrict__ gma, const float* __restrict__ bta,
     const float* __restrict__ mea, const float* __restrict__ var,
     const float* __restrict__ hres, float* __restrict__ hout){
  int node = (blockIdx.x*256 + threadIdx.x) >> 6;
  int lane = threadIdx.x & 63;
  if (node >= NN) return;
  int rb = rp[node], re = rp[node+1];
  float edn[4], esn[4];
  { float4 t = *(const float4*)(ed4 + (size_t)node*4); edn[0]=t.x; edn[1]=t.y; edn[2]=t.z; edn[3]=t.w; }
  { float4 t = *(const float4*)(es4 + (size_t)node*4); esn[0]=t.x; esn[1]=t.y; esn[2]=t.z; esn[3]=t.w; }

  // pass A: segment max (self-loop included)
  float m[4];
  #pragma unroll
  for (int h = 0; h < 4; h++) m[h] = lrelu(esn[h] + edn[h]);
  for (int e = rb; e < re; e++){
    int s = col[e];
    float4 t = *(const float4*)(es4 + (size_t)s*4);
    float a[4] = {t.x, t.y, t.z, t.w};
    #pragma unroll
    for (int h = 0; h < 4; h++) m[h] = fmaxf(m[h], lrelu(a[h] + edn[h]));
  }

  // pass B: accumulate exp-weights and unnormalized messages
  float denom[4], acc[4];
  const float* hr = hf + (size_t)node*256;
  #pragma unroll
  for (int h = 0; h < 4; h++){
    float ex = __expf(lrelu(esn[h] + edn[h]) - m[h]);
    denom[h] = ex;
    acc[h] = ex * hr[h*64 + lane];
  }
  for (int e = rb; e < re; e++){
    int s = col[e];
    float4 t = *(const float4*)(es4 + (size_t)s*4);
    float a[4] = {t.x, t.y, t.z, t.w};
    const float* hs = hf + (size_t)s*256;
    #pragma unroll
    for (int h = 0; h < 4; h++){
      float ex = __expf(lrelu(a[h] + edn[h]) - m[h]);
      denom[h] += ex;
      acc[h] += ex * hs[h*64 + lane];
    }
  }

  float o = 0.f;
  #pragma unroll
  for (int h = 0; h < 4; h++) o += acc[h] / denom[h];
  o = 0.25f*o + bias[lane];                                        // head mean + bias
  o = (o - mea[lane]) * rsqrtf(var[lane] + 1e-5f) * gma[lane] + bta[lane];  // BN (eval)
  o = o > 0.f ? o : (__expf(o) - 1.f);                             // ELU
  if (hres) o += hres[(size_t)node*64 + lane];                     // residual
  hout[(size_t)node*64 + lane] = o;
}

// ---------------- pooling (batch sorted -> contiguous ranges) ----------------
__global__ __launch_bounds__(64) void k_pool(const float* __restrict__ h, const int* __restrict__ gstart,
                                             float* __restrict__ pooled){
  int g = blockIdx.x; int lane = threadIdx.x;
  int beg = gstart[g], end = gstart[g+1];
  float acc = 0.f;
  for (int n = beg; n < end; n++) acc += h[(size_t)n*64 + lane];
  float cnt = (float)(end - beg);
  pooled[(size_t)g*64 + lane] = acc / fmaxf(cnt, 1.f);
}

// ---------------- output MLP ----------------
__global__ __launch_bounds__(256) void k_mlp(const float* __restrict__ pooled, const float* __restrict__ W1,
                                             const float* __restrict__ b1, const float* __restrict__ W2,
                                             const float* __restrict__ b2, float* __restrict__ out){
  int g = blockIdx.x*256 + threadIdx.x;
  if (g >= GG) return;
  const float* p = pooled + (size_t)g*64;
  float o = 0.f;
  for (int j = 0; j < 32; j++){
    float z = b1[j];
    for (int c = 0; c < 64; c++) z += p[c] * W1[c*32 + j];
    z = z > 0.f ? z : (__expf(z) - 1.f);
    o += z * W2[j];
  }
  out[g] = o + b2[0];
}

extern "C" void kernel_launch(void* const* d_in, const int* in_sizes, int n_in,
                              void* d_out, int out_size, void* d_ws, size_t ws_size,
                              hipStream_t stream) {
  const float* x    = (const float*)d_in[0];
  const int*   ei   = (const int*)d_in[1];
  const int*   batch= (const int*)d_in[2];
  const float* g0W  = (const float*)d_in[3];
  const float* g0as = (const float*)d_in[4];
  const float* g0ad = (const float*)d_in[5];
  const float* g0b  = (const float*)d_in[6];
  const float* bn0g = (const float*)d_in[7];
  const float* bn0b = (const float*)d_in[8];
  const float* bn0m = (const float*)d_in[9];
  const float* bn0v = (const float*)d_in[10];
  const float* gW   = (const float*)d_in[11];
  const float* gas  = (const float*)d_in[12];
  const float* gad  = (const float*)d_in[13];
  const float* gb   = (const float*)d_in[14];
  const float* bng  = (const float*)d_in[15];
  const float* bnb  = (const float*)d_in[16];
  const float* bnm  = (const float*)d_in[17];
  const float* bnv  = (const float*)d_in[18];
  const float* W1   = (const float*)d_in[19];
  const float* b1   = (const float*)d_in[20];
  const float* W2   = (const float*)d_in[21];
  const float* b2   = (const float*)d_in[22];
  float* out = (float*)d_out;
  (void)in_sizes; (void)n_in; (void)out_size; (void)ws_size;

  char* base = (char*)d_ws; size_t off = 0;
  auto alloc = [&](size_t b)->void*{ void* p = base + off; off = (off + b + 255) & ~(size_t)255; return p; };
  float* h_feat = (float*)alloc((size_t)NN*256*4);   // 153.6 MB
  float* h_cur  = (float*)alloc((size_t)NN*64*4);    // 38.4 MB
  float* es     = (float*)alloc((size_t)NN*4*4);
  float* ed     = (float*)alloc((size_t)NN*4*4);
  int*   deg    = (int*)alloc((size_t)NN*4);
  int*   fill   = (int*)alloc((size_t)NN*4);
  int*   rp     = (int*)alloc((size_t)(NN+1)*4);
  int*   col    = (int*)alloc((size_t)EE*4);
  int*   bsum   = (int*)alloc(1024*4);
  int*   gstart = (int*)alloc((size_t)(GG+1)*4);
  float* pooled = (float*)alloc((size_t)GG*64*4);

  const int* esrc = ei;
  const int* edst = ei + EE;

  hipMemsetAsync(deg, 0, (size_t)NN*4, stream);
  hipMemsetAsync(fill, 0, (size_t)NN*4, stream);

  int nb1 = (NN + 255)/256;   // 586
  k_count<<<(EE+255)/256, 256, 0, stream>>>(edst, deg);
  k_scan1<<<nb1, 256, 0, stream>>>(deg, rp, bsum);
  k_scan2<<<1, 1024, 0, stream>>>(bsum, nb1);
  k_scan3<<<nb1, 256, 0, stream>>>(rp, bsum);
  k_fill<<<(EE+255)/256, 256, 0, stream>>>(esrc, edst, rp, fill, col);
  k_gstart<<<(GG+256)/256, 256, 0, stream>>>(batch, gstart);

  int ngemm = (NN + 15)/16;      // 9375
  int nwave = (NN + 3)/4;        // 37500 (wave per node, 4 waves/block)

  // layer 0
  k_gemm<INF><<<ngemm, 256, 0, stream>>>(x, g0W, h_feat);
  k_esed<<<nwave, 256, 0, stream>>>(h_feat, g0as, g0ad, es, ed);
  k_aggr<<<nwave, 256, 0, stream>>>(h_feat, es, ed, rp, col, g0b, bn0g, bn0b, bn0m, bn0v,
                                    nullptr, h_cur);
  // layers 1..3 (residual, in-place safe: each thread reads its own element before writing)
  for (int i = 0; i < 3; i++){
    k_gemm<CC><<<ngemm, 256, 0, stream>>>(h_cur, gW + (size_t)i*64*256, h_feat);
    k_esed<<<nwave, 256, 0, stream>>>(h_feat, gas + (size_t)i*256, gad + (size_t)i*256, es, ed);
    k_aggr<<<nwave, 256, 0, stream>>>(h_feat, es, ed, rp, col, gb + (size_t)i*64,
                                      bng + (size_t)i*64, bnb + (size_t)i*64,
                                      bnm + (size_t)i*64, bnv + (size_t)i*64,
                                      h_cur, h_cur);
  }

  k_pool<<<GG, 64, 0, stream>>>(h_cur, gstart, pooled);
  k_mlp<<<(GG+255)/256, 256, 0, stream>>>(pooled, W1, b1, W2, b2, out);
}

// Round 2
// 1080.550 us; speedup vs baseline: 1.3494x; 1.3494x over previous
//
#include <hip/hip_runtime.h>

#define NN 150000
#define EE 600000
#define HH 4
#define CC 64
#define GG 4096
#define INF 9

__device__ __forceinline__ float lrelu(float a){ return a > 0.f ? a : 0.2f*a; }

// ---------------- CSR build ----------------
__global__ __launch_bounds__(256) void k_count(const int* __restrict__ dst, int* __restrict__ deg){
  int e = blockIdx.x*256 + threadIdx.x;
  if (e < EE) atomicAdd(&deg[dst[e]], 1);
}

__global__ __launch_bounds__(256) void k_scan1(const int* __restrict__ deg, int* __restrict__ excl, int* __restrict__ bsum){
  __shared__ int s[256];
  int tid = threadIdx.x, gid = blockIdx.x*256 + tid;
  int v = (gid < NN) ? deg[gid] : 0;
  s[tid] = v; __syncthreads();
  for (int off = 1; off < 256; off <<= 1){
    int t = (tid >= off) ? s[tid-off] : 0; __syncthreads();
    s[tid] += t; __syncthreads();
  }
  if (gid < NN) excl[gid] = s[tid] - v;   // block-local exclusive
  if (tid == 255) bsum[blockIdx.x] = s[255];
}

__global__ __launch_bounds__(1024) void k_scan2(int* __restrict__ bsum, int nb){
  __shared__ int s[1024];
  int tid = threadIdx.x;
  int v = (tid < nb) ? bsum[tid] : 0;
  s[tid] = v; __syncthreads();
  for (int off = 1; off < 1024; off <<= 1){
    int t = (tid >= off) ? s[tid-off] : 0; __syncthreads();
    s[tid] += t; __syncthreads();
  }
  if (tid < nb) bsum[tid] = s[tid] - v;   // exclusive block offsets
}

__global__ __launch_bounds__(256) void k_scan3(int* __restrict__ rp, const int* __restrict__ bsum){
  int gid = blockIdx.x*256 + threadIdx.x;
  if (gid < NN) rp[gid] += bsum[blockIdx.x];
  if (gid == 0) rp[NN] = EE;
}

__global__ __launch_bounds__(256) void k_fill(const int* __restrict__ src, const int* __restrict__ dst,
                                              const int* __restrict__ rp, int* __restrict__ fill,
                                              int* __restrict__ col){
  int e = blockIdx.x*256 + threadIdx.x;
  if (e < EE){
    int d = dst[e];
    int pos = rp[d] + atomicAdd(&fill[d], 1);
    col[pos] = src[e];
  }
}

// batch is sorted; gstart[g] = first node of graph g (gstart[GG] = NN)
__global__ __launch_bounds__(256) void k_gstart(const int* __restrict__ batch, int* __restrict__ gstart){
  int g = blockIdx.x*256 + threadIdx.x;
  if (g > GG) return;
  int lo = 0, hi = NN;
  while (lo < hi){ int mid = (lo+hi) >> 1; if (batch[mid] < g) lo = mid+1; else hi = mid; }
  gstart[g] = lo;
}

// ---------------- fold attention vectors into weights ----------------
// Wa0[k][j] = sum_c g0W[k,256][h*64+c] * a[h][c],  h=j&3, a = asrc (j<4) or adst (j>=4)
// Wa [i][k][j] likewise for gat_W[i] (K=64)
__global__ __launch_bounds__(256) void k_fold(const float* __restrict__ g0W, const float* __restrict__ g0as,
    const float* __restrict__ g0ad, const float* __restrict__ gW, const float* __restrict__ gas,
    const float* __restrict__ gad, float* __restrict__ Wa0, float* __restrict__ Wa){
  int t = blockIdx.x*256 + threadIdx.x;
  if (t < INF*8){
    int k = t >> 3, j = t & 7, h = j & 3;
    const float* a = (j < 4) ? g0as : g0ad;
    float s = 0.f;
    for (int c = 0; c < 64; c++) s += g0W[k*256 + h*64 + c] * a[h*64 + c];
    Wa0[k*8 + j] = s;
  } else if (t < INF*8 + 3*64*8){
    int u = t - INF*8;
    int i = u / 512, r = u % 512, k = r >> 3, j = r & 7, h = j & 3;
    const float* a = ((j < 4) ? gas : gad) + (size_t)i*256;
    float s = 0.f;
    for (int c = 0; c < 64; c++) s += gW[(size_t)i*64*256 + k*256 + h*64 + c] * a[h*64 + c];
    Wa[(size_t)i*512 + k*8 + j] = s;
  }
}

// ---------------- feature transform + fused logits ----------------
// h_feat[N,256] = hin[N,K] @ W[K,256];  es/ed[N,4] = hin @ Wa (folded)
template<int K>
__global__ __launch_bounds__(256) void k_gemm(const float* __restrict__ hin, const float* __restrict__ W,
                                              const float* __restrict__ Wa,
                                              float* __restrict__ hf, float* __restrict__ es,
                                              float* __restrict__ ed){
  int base = blockIdx.x * 16;
  int t = threadIdx.x;
  __shared__ float xs[16][K+1];
  for (int i = t; i < 16*K; i += 256){
    int node = base + i/K;
    xs[i/K][i%K] = (node < NN) ? hin[(size_t)node*K + i%K] : 0.f;
  }
  __syncthreads();
  float acc[16];
  #pragma unroll
  for (int i = 0; i < 16; i++) acc[i] = 0.f;
  for (int k = 0; k < K; k++){
    float w = W[k*256 + t];
    #pragma unroll
    for (int i = 0; i < 16; i++) acc[i] += xs[i][k] * w;
  }
  #pragma unroll
  for (int i = 0; i < 16; i++){
    int node = base + i;
    if (node < NN) hf[(size_t)node*256 + t] = acc[i];
  }
  // fused logits: threads 0..127, one (node, j) scalar each
  if (t < 128){
    int ni = t >> 3, j = t & 7;
    int node = base + ni;
    if (node < NN){
      float s = 0.f;
      for (int k = 0; k < K; k++) s += xs[ni][k] * Wa[k*8 + j];
      if (j < 4) es[(size_t)node*4 + j] = s;
      else       ed[(size_t)node*4 + (j-4)] = s;
    }
  }
}

// ---------------- attention + aggregation + epilogue (one wave per node) ----------------
// single pass: softmax shift-invariance, alpha bounded -> exp directly, no segment max
__global__ __launch_bounds__(256) void k_aggr(const float* __restrict__ hf, const float* __restrict__ es4,
     const float* __restrict__ ed4, const int* __restrict__ rp, const int* __restrict__ col,
     const float* __restrict__ bias, const float* __restrict__ gma, const float* __restrict__ bta,
     const float* __restrict__ mea, const float* __restrict__ var,
     const float* __restrict__ hres, float* __restrict__ hout){
  int node = (blockIdx.x*256 + threadIdx.x) >> 6;
  int lane = threadIdx.x & 63;
  if (node >= NN) return;
  node = __builtin_amdgcn_readfirstlane(node);   // wave-uniform -> SGPR address chains
  int rb = rp[node], re = rp[node+1];
  float4 edt = *(const float4*)(ed4 + (size_t)node*4);
  float edn[4] = {edt.x, edt.y, edt.z, edt.w};
  float4 est = *(const float4*)(es4 + (size_t)node*4);

  float denom[4], acc[4];
  const float* hr = hf + (size_t)node*256;
  {
    float a[4] = {est.x, est.y, est.z, est.w};
    #pragma unroll
    for (int h = 0; h < 4; h++){
      float ex = __expf(lrelu(a[h] + edn[h]));
      denom[h] = ex;
      acc[h] = ex * hr[h*64 + lane];
    }
  }

  int e = rb;
  if (e < re){
    // software-pipelined: edge e+1's col/es/h loads issued while edge e accumulates
    int sA = col[e];
    float4 tA = *(const float4*)(es4 + (size_t)sA*4);
    const float* hsA = hf + (size_t)sA*256;
    float hA0 = hsA[0*64+lane], hA1 = hsA[1*64+lane], hA2 = hsA[2*64+lane], hA3 = hsA[3*64+lane];
    for (; e < re; ){
      int en = e + 1;
      int sB = (en < re) ? col[en] : sA;
      float4 tB = *(const float4*)(es4 + (size_t)sB*4);
      const float* hsB = hf + (size_t)sB*256;
      float hB0 = hsB[0*64+lane], hB1 = hsB[1*64+lane], hB2 = hsB[2*64+lane], hB3 = hsB[3*64+lane];
      float ex0 = __expf(lrelu(tA.x + edn[0])); denom[0] += ex0; acc[0] += ex0 * hA0;
      float ex1 = __expf(lrelu(tA.y + edn[1])); denom[1] += ex1; acc[1] += ex1 * hA1;
      float ex2 = __expf(lrelu(tA.z + edn[2])); denom[2] += ex2; acc[2] += ex2 * hA2;
      float ex3 = __expf(lrelu(tA.w + edn[3])); denom[3] += ex3; acc[3] += ex3 * hA3;
      tA = tB; hA0 = hB0; hA1 = hB1; hA2 = hB2; hA3 = hB3;
      e = en;
    }
  }

  float o = 0.f;
  #pragma unroll
  for (int h = 0; h < 4; h++) o += acc[h] / denom[h];
  o = 0.25f*o + bias[lane];                                        // head mean + bias
  o = (o - mea[lane]) * rsqrtf(var[lane] + 1e-5f) * gma[lane] + bta[lane];  // BN (eval)
  o = o > 0.f ? o : (__expf(o) - 1.f);                             // ELU
  if (hres) o += hres[(size_t)node*64 + lane];                     // residual
  hout[(size_t)node*64 + lane] = o;
}

// ---------------- pooling (batch sorted -> contiguous ranges) ----------------
__global__ __launch_bounds__(64) void k_pool(const float* __restrict__ h, const int* __restrict__ gstart,
                                             float* __restrict__ pooled){
  int g = blockIdx.x; int lane = threadIdx.x;
  int beg = gstart[g], end = gstart[g+1];
  float acc = 0.f;
  for (int n = beg; n < end; n++) acc += h[(size_t)n*64 + lane];
  float cnt = (float)(end - beg);
  pooled[(size_t)g*64 + lane] = acc / fmaxf(cnt, 1.f);
}

// ---------------- output MLP ----------------
__global__ __launch_bounds__(256) void k_mlp(const float* __restrict__ pooled, const float* __restrict__ W1,
                                             const float* __restrict__ b1, const float* __restrict__ W2,
                                             const float* __restrict__ b2, float* __restrict__ out){
  int g = blockIdx.x*256 + threadIdx.x;
  if (g >= GG) return;
  const float* p = pooled + (size_t)g*64;
  float o = 0.f;
  for (int j = 0; j < 32; j++){
    float z = b1[j];
    for (int c = 0; c < 64; c++) z += p[c] * W1[c*32 + j];
    z = z > 0.f ? z : (__expf(z) - 1.f);
    o += z * W2[j];
  }
  out[g] = o + b2[0];
}

extern "C" void kernel_launch(void* const* d_in, const int* in_sizes, int n_in,
                              void* d_out, int out_size, void* d_ws, size_t ws_size,
                              hipStream_t stream) {
  const float* x    = (const float*)d_in[0];
  const int*   ei   = (const int*)d_in[1];
  const int*   batch= (const int*)d_in[2];
  const float* g0W  = (const float*)d_in[3];
  const float* g0as = (const float*)d_in[4];
  const float* g0ad = (const float*)d_in[5];
  const float* g0b  = (const float*)d_in[6];
  const float* bn0g = (const float*)d_in[7];
  const float* bn0b = (const float*)d_in[8];
  const float* bn0m = (const float*)d_in[9];
  const float* bn0v = (const float*)d_in[10];
  const float* gW   = (const float*)d_in[11];
  const float* gas  = (const float*)d_in[12];
  const float* gad  = (const float*)d_in[13];
  const float* gb   = (const float*)d_in[14];
  const float* bng  = (const float*)d_in[15];
  const float* bnb  = (const float*)d_in[16];
  const float* bnm  = (const float*)d_in[17];
  const float* bnv  = (const float*)d_in[18];
  const float* W1   = (const float*)d_in[19];
  const float* b1   = (const float*)d_in[20];
  const float* W2   = (const float*)d_in[21];
  const float* b2   = (const float*)d_in[22];
  float* out = (float*)d_out;
  (void)in_sizes; (void)n_in; (void)out_size; (void)ws_size;

  char* base = (char*)d_ws; size_t off = 0;
  auto alloc = [&](size_t b)->void*{ void* p = base + off; off = (off + b + 255) & ~(size_t)255; return p; };
  float* h_feat = (float*)alloc((size_t)NN*256*4);   // 153.6 MB
  float* h_cur  = (float*)alloc((size_t)NN*64*4);    // 38.4 MB
  float* es     = (float*)alloc((size_t)NN*4*4);
  float* ed     = (float*)alloc((size_t)NN*4*4);
  int*   deg    = (int*)alloc((size_t)NN*4);
  int*   fill   = (int*)alloc((size_t)NN*4);
  int*   rp     = (int*)alloc((size_t)(NN+1)*4);
  int*   col    = (int*)alloc((size_t)EE*4);
  int*   bsum   = (int*)alloc(1024*4);
  int*   gstart = (int*)alloc((size_t)(GG+1)*4);
  float* pooled = (float*)alloc((size_t)GG*64*4);
  float* Wa0    = (float*)alloc((size_t)INF*8*4);
  float* Wa     = (float*)alloc((size_t)3*64*8*4);

  const int* esrc = ei;
  const int* edst = ei + EE;

  hipMemsetAsync(deg, 0, (size_t)NN*4, stream);
  hipMemsetAsync(fill, 0, (size_t)NN*4, stream);

  int nb1 = (NN + 255)/256;   // 586
  k_count<<<(EE+255)/256, 256, 0, stream>>>(edst, deg);
  k_scan1<<<nb1, 256, 0, stream>>>(deg, rp, bsum);
  k_scan2<<<1, 1024, 0, stream>>>(bsum, nb1);
  k_scan3<<<nb1, 256, 0, stream>>>(rp, bsum);
  k_fill<<<(EE+255)/256, 256, 0, stream>>>(esrc, edst, rp, fill, col);
  k_gstart<<<(GG+256)/256, 256, 0, stream>>>(batch, gstart);
  k_fold<<<7, 256, 0, stream>>>(g0W, g0as, g0ad, gW, gas, gad, Wa0, Wa);

  int ngemm = (NN + 15)/16;      // 9375
  int nwave = (NN + 3)/4;        // 37500 (wave per node, 4 waves/block)

  // layer 0
  k_gemm<INF><<<ngemm, 256, 0, stream>>>(x, g0W, Wa0, h_feat, es, ed);
  k_aggr<<<nwave, 256, 0, stream>>>(h_feat, es, ed, rp, col, g0b, bn0g, bn0b, bn0m, bn0v,
                                    nullptr, h_cur);
  // layers 1..3 (residual, in-place safe: each thread reads its own element before writing)
  for (int i = 0; i < 3; i++){
    k_gemm<CC><<<ngemm, 256, 0, stream>>>(h_cur, gW + (size_t)i*64*256, Wa + (size_t)i*512, h_feat, es, ed);
    k_aggr<<<nwave, 256, 0, stream>>>(h_feat, es, ed, rp, col, gb + (size_t)i*64,
                                      bng + (size_t)i*64, bnb + (size_t)i*64,
                                      bnm + (size_t)i*64, bnv + (size_t)i*64,
                                      h_cur, h_cur);
  }

  k_pool<<<GG, 64, 0, stream>>>(h_cur, gstart, pooled);
  k_mlp<<<(GG+255)/256, 256, 0, stream>>>(pooled, W1, b1, W2, b2, out);
}